// Round 3
// baseline (9.872 us; speedup 1.0000x reference)
//
#include <hip/hip_runtime.h>

// out[c,h,v] = (h==0 ? y[v,c] : fifo[c, h-1, v]) + sum_{i=1..8} fifo[c, i*63+h-1, v]
// y[v,c] = sum_{p<3,u<64} x[p*1024+c, u] * graph[p, u, v]
// x (3072,64) f32; graph (192,64) f32; fifo (1024,512,64) f32; out (1024,8,64) f32.
//
// 256 blocks x 512 threads; each block handles 4 consecutive c.
// Per c: 128 threads, h = r>>4 (0..7), q = r&15 (v-quad, float4 lanes).
// y-reduction (K=192) split 8 ways across h-groups, combined via LDS.

#define P 3
#define C 1024
#define V 64
#define F 512
#define K 9
#define D 63
#define HOUT 8
#define CPB 4   // c per block

__global__ __launch_bounds__(512) void stgcn_kernel(
    const float* __restrict__ x,       // (P*C, V)
    const float4* __restrict__ g4,     // (P*V, 16) float4 view of graph
    const float4* __restrict__ fifo4,  // (C*F, 16) float4 view
    float4* __restrict__ out4)         // (C*HOUT, 16) float4 view
{
    const int t  = threadIdx.x;   // 0..511
    const int cl = t >> 7;        // 0..3
    const int r  = t & 127;       // 0..127
    const int h  = r >> 4;        // 0..7
    const int q  = r & 15;        // 0..15
    const int c  = blockIdx.x * CPB + cl;

    __shared__ float  xs[CPB][P * V];     // 3 KB
    __shared__ float4 part[CPB][8][16];   // 8 KB

    // Stage x rows for this block's 4 c's (each 128-thread group loads its own c).
    for (int idx = r; idx < P * V; idx += 128) {
        xs[cl][idx] = x[((idx >> 6) * C + c) * V + (idx & 63)];
    }
    __syncthreads();

    // Partial y: group h covers pu in [h*24, h*24+24).
    float ax = 0.f, ay = 0.f, az = 0.f, aw = 0.f;
    const int pu0 = h * 24;
    #pragma unroll
    for (int i = 0; i < 24; ++i) {
        const int pu = pu0 + i;
        const float  xv = xs[cl][pu];
        const float4 gg = g4[pu * 16 + q];   // L2-resident, coalesced
        ax = fmaf(xv, gg.x, ax);
        ay = fmaf(xv, gg.y, ay);
        az = fmaf(xv, gg.z, az);
        aw = fmaf(xv, gg.w, aw);
    }
    part[cl][h][q] = make_float4(ax, ay, az, aw);

    // FIFO taps: base row (h-1); taps at (h-1) + i*63, i=1..8.
    const long base = (long)c * (F * 16) + (long)(h - 1) * 16 + q;  // float4 units
    float4 f0;
    if (h > 0) {
        f0 = fifo4[base];
    }

    float4 tap[K - 1];
    #pragma unroll
    for (int i = 1; i < K; ++i) {
        tap[i - 1] = fifo4[base + (long)i * (D * 16)];
    }

    __syncthreads();

    float rx, ry, rz, rw;
    if (h == 0) {
        float4 s = part[cl][0][q];
        rx = s.x; ry = s.y; rz = s.z; rw = s.w;
        #pragma unroll
        for (int g = 1; g < 8; ++g) {
            float4 pgq = part[cl][g][q];
            rx += pgq.x; ry += pgq.y; rz += pgq.z; rw += pgq.w;
        }
    } else {
        rx = f0.x; ry = f0.y; rz = f0.z; rw = f0.w;
    }

    #pragma unroll
    for (int i = 0; i < K - 1; ++i) {
        rx += tap[i].x; ry += tap[i].y; rz += tap[i].z; rw += tap[i].w;
    }

    out4[(c * HOUT + h) * 16 + q] = make_float4(rx, ry, rz, rw);
}

extern "C" void kernel_launch(void* const* d_in, const int* in_sizes, int n_in,
                              void* d_out, int out_size, void* d_ws, size_t ws_size,
                              hipStream_t stream) {
    const float*  x     = (const float*)d_in[0];
    const float4* graph = (const float4*)d_in[1];
    const float4* fifo  = (const float4*)d_in[2];
    float4* out = (float4*)d_out;

    stgcn_kernel<<<C / CPB, 512, 0, stream>>>(x, graph, fifo, out);
}